// Round 1
// baseline (21687.447 us; speedup 1.0000x reference)
//
#include <hip/hip_runtime.h>
#include <math.h>

#define NB 128
#define NKK 64
#define ND 1536
#define NEM 512
#define NH 1024
#define NA 1024
#define NVOC 10000
#define NT 30

__device__ __forceinline__ float sigf(float x) { return 1.0f / (1.0f + expf(-x)); }

// ---------------- sort + target/lens outputs ----------------
__global__ void sort_kernel(const int* __restrict__ cap, const int* __restrict__ w,
                            float* __restrict__ out_target, float* __restrict__ out_lens,
                            int* __restrict__ order, int* __restrict__ lens_s) {
    __shared__ int lcap[NB];
    __shared__ int sord[NB];
    int b = threadIdx.x;
    lcap[b] = cap[b];
    __syncthreads();
    int lb = lcap[b];
    int pos = 0;
    for (int j = 0; j < NB; j++) {
        int lj = lcap[j];
        if (lj > lb || (lj == lb && j < b)) pos++;
    }
    sord[pos] = b;
    __syncthreads();
    int src = sord[b];
    order[b] = src;
    int ln = lcap[src] - 1;
    lens_s[b] = ln;
    out_lens[b] = (float)ln;
    for (int j = 0; j < NT; j++)
        out_target[b * NT + j] = (float)w[src * (NT + 1) + j + 1];
}

// ---------------- init: bias sums + zero h/c ----------------
__global__ void init_kernel(const float* __restrict__ b_ih, const float* __restrict__ b_hh,
                            const float* __restrict__ b_xg, const float* __restrict__ b_hg,
                            float* __restrict__ bgates, float* __restrict__ bsg,
                            float* __restrict__ h, float* __restrict__ c) {
    int tid = blockIdx.x * 256 + threadIdx.x;
    if (tid < 4 * NH) bgates[tid] = b_ih[tid] + b_hh[tid];
    if (tid < NH) bsg[tid] = b_xg[tid] + b_hg[tid];
    if (tid < NB * NH) { h[tid] = 0.f; c[tid] = 0.f; }
}

// ---------------- mean over K (sorted order) ----------------
__global__ void meanim_kernel(const float* __restrict__ im, const int* __restrict__ order,
                              float* __restrict__ meanim) {
    int b = blockIdx.x;
    int src = order[b];
    const float* base = im + (size_t)src * NKK * ND;
    for (int d = threadIdx.x; d < ND; d += 256) {
        float acc = 0.f;
        for (int k = 0; k < NKK; k++) acc += base[(size_t)k * ND + d];
        meanim[b * ND + d] = acc * (1.0f / NKK);
    }
}

// ---------------- generic fp32 GEMM: C = gather(A) @ [B1;B2] + bias (relu?) ----------------
__global__ __launch_bounds__(256) void gemm_f32(
    const float* __restrict__ A, const float* __restrict__ B1, const float* __restrict__ B2,
    int ksplit, const float* __restrict__ bias, float* __restrict__ C,
    int M, int N, int K, int lda, int ldb, int ldc,
    const int* __restrict__ order, int group, int relu) {
    __shared__ float As[16][68];
    __shared__ float Bs[16][68];
    const int tid = threadIdx.x;
    const int tx = tid & 15, ty = tid >> 4;
    const int m0 = blockIdx.y * 64, n0 = blockIdx.x * 64;

    const int arow = tid >> 2;          // 0..63
    const int akk = (tid & 3) * 4;      // 0,4,8,12
    const bool arow_ok = (m0 + arow) < M;
    int asrc = m0 + arow;
    if (arow_ok && order) asrc = order[asrc / group] * group + (asrc % group);

    const int brow = tid >> 4;          // 0..15
    const int bcol = (tid & 15) * 4;    // 0..60

    float acc[4][4] = {};

    for (int k0 = 0; k0 < K; k0 += 16) {
        float4 av = make_float4(0.f, 0.f, 0.f, 0.f);
        if (arow_ok) av = *(const float4*)(A + (size_t)asrc * lda + k0 + akk);
        As[akk + 0][arow] = av.x; As[akk + 1][arow] = av.y;
        As[akk + 2][arow] = av.z; As[akk + 3][arow] = av.w;

        int kr = k0 + brow;
        const float* Bp = B1;
        if (B2 && kr >= ksplit) { Bp = B2; kr -= ksplit; }
        int nc = n0 + bcol;
        float4 bv;
        if (nc + 3 < N) {
            bv = *(const float4*)(Bp + (size_t)kr * ldb + nc);
        } else {
            float tmp[4] = {0.f, 0.f, 0.f, 0.f};
            for (int j = 0; j < 4; j++) if (nc + j < N) tmp[j] = Bp[(size_t)kr * ldb + nc + j];
            bv = make_float4(tmp[0], tmp[1], tmp[2], tmp[3]);
        }
        Bs[brow][bcol + 0] = bv.x; Bs[brow][bcol + 1] = bv.y;
        Bs[brow][bcol + 2] = bv.z; Bs[brow][bcol + 3] = bv.w;
        __syncthreads();

#pragma unroll
        for (int kk = 0; kk < 16; kk++) {
            float a[4], bb[4];
#pragma unroll
            for (int i = 0; i < 4; i++) a[i] = As[kk][ty * 4 + i];
#pragma unroll
            for (int j = 0; j < 4; j++) bb[j] = Bs[kk][tx * 4 + j];
#pragma unroll
            for (int i = 0; i < 4; i++)
#pragma unroll
                for (int j = 0; j < 4; j++) acc[i][j] += a[i] * bb[j];
        }
        __syncthreads();
    }

    for (int i = 0; i < 4; i++) {
        int r = m0 + ty * 4 + i;
        if (r >= M) continue;
        for (int j = 0; j < 4; j++) {
            int cidx = n0 + tx * 4 + j;
            if (cidx >= N) continue;
            float v = acc[i][j];
            if (bias) v += bias[cidx];
            if (relu) v = fmaxf(v, 0.f);
            C[(size_t)r * ldc + cidx] = v;
        }
    }
}

// ---------------- build x = [emb[w_t] | g | h] (128 x 2048) ----------------
__global__ void gather_x(const float* __restrict__ emb, const float* __restrict__ g,
                         const float* __restrict__ h, const int* __restrict__ w,
                         const int* __restrict__ order, int t, float* __restrict__ xbuf) {
    int b = blockIdx.x;
    int wid = w[order[b] * (NT + 1) + t];
    const float* erow = emb + (size_t)wid * NEM;
    for (int col = threadIdx.x; col < 2048; col += 256) {
        float v;
        if (col < NEM) v = erow[col];
        else if (col < 2 * NEM) v = g[b * NEM + col - NEM];
        else v = h[b * NH + col - 2 * NEM];
        xbuf[b * 2048 + col] = v;
    }
}

// ---------------- LSTM pointwise: c,h updated in place; s produced ----------------
__global__ void lstm_pointwise(const float* __restrict__ gates, const float* __restrict__ sg_pre,
                               float* __restrict__ c, float* __restrict__ h, float* __restrict__ s) {
    int tid = blockIdx.x * 256 + threadIdx.x;   // b*NH + j
    int b = tid >> 10, j = tid & 1023;
    const float* gr = gates + (size_t)b * 4 * NH;
    float ig = sigf(gr[j]);
    float fg = sigf(gr[NH + j]);
    float gg = tanhf(gr[2 * NH + j]);
    float og = sigf(gr[3 * NH + j]);
    float cn = fg * c[tid] + ig * gg;
    float hn = og * tanhf(cn);
    float sv = sigf(sg_pre[tid]) * tanhf(cn);
    c[tid] = cn; h[tid] = hn; s[tid] = sv;
}

// ---------------- attention: zv/zs -> softmax(65) -> ctx -> z_t ----------------
__global__ __launch_bounds__(256) void attn_kernel(
    const float* __restrict__ VA, const float* __restrict__ V, const float* __restrict__ hp,
    const float* __restrict__ sws, const float* __restrict__ wa,
    const float* __restrict__ s, const float* __restrict__ h, float* __restrict__ z) {
    __shared__ float hp_l[NH];
    __shared__ float wa_l[NA];
    __shared__ float zscore[NKK + 1];
    __shared__ float alpha_s[NKK + 1];
    int b = blockIdx.x;
    for (int i = threadIdx.x; i < NH; i += 256) { hp_l[i] = hp[b * NH + i]; wa_l[i] = wa[i]; }
    __syncthreads();
    int wave = threadIdx.x >> 6, lane = threadIdx.x & 63;
    for (int k = wave; k < NKK; k += 4) {
        const float* va = VA + ((size_t)(b * NKK + k)) * NA;
        float p = 0.f;
        for (int a = lane; a < NA; a += 64) p += tanhf(va[a] + hp_l[a]) * wa_l[a];
        for (int off = 32; off; off >>= 1) p += __shfl_down(p, off);
        if (lane == 0) zscore[k] = p;
    }
    if (wave == 0) {
        const float* sp = sws + (size_t)b * NA;
        float p = 0.f;
        for (int a = lane; a < NA; a += 64) p += tanhf(sp[a] + hp_l[a]) * wa_l[a];
        for (int off = 32; off; off >>= 1) p += __shfl_down(p, off);
        if (lane == 0) zscore[NKK] = p;
    }
    __syncthreads();
    if (threadIdx.x == 0) {
        float mx = zscore[0];
        for (int i = 1; i <= NKK; i++) mx = fmaxf(mx, zscore[i]);
        float ssum = 0.f;
        for (int i = 0; i <= NKK; i++) { float e = expf(zscore[i] - mx); alpha_s[i] = e; ssum += e; }
        float inv = 1.f / ssum;
        for (int i = 0; i <= NKK; i++) alpha_s[i] *= inv;
    }
    __syncthreads();
    float beta = alpha_s[NKK];
    for (int j = threadIdx.x; j < NH; j += 256) {
        float ctx = 0.f;
        const float* vp = V + ((size_t)b * NKK) * NH + j;
        for (int k = 0; k < NKK; k++) ctx += alpha_s[k] * vp[(size_t)k * NH];
        z[b * NH + j] = beta * s[b * NH + j] + (1.f - beta) * ctx + h[b * NH + j];
    }
}

// ---------------- vocab softmax + mask + write predictions ----------------
__global__ __launch_bounds__(256) void vocab_softmax(const float* __restrict__ logits,
                                                     const int* __restrict__ lens_s, int t,
                                                     float* __restrict__ pred) {
    int b = blockIdx.x;
    float* out = pred + (size_t)b * NT * NVOC + (size_t)t * NVOC;
    if (t >= lens_s[b]) {
        for (int v = threadIdx.x; v < NVOC; v += 256) out[v] = 0.f;
        return;
    }
    const float* lg = logits + (size_t)b * NVOC;
    float mx = -1e30f;
    for (int v = threadIdx.x; v < NVOC; v += 256) mx = fmaxf(mx, lg[v]);
    __shared__ float sred[4];
    for (int off = 32; off; off >>= 1) mx = fmaxf(mx, __shfl_down(mx, off));
    if ((threadIdx.x & 63) == 0) sred[threadIdx.x >> 6] = mx;
    __syncthreads();
    mx = fmaxf(fmaxf(sred[0], sred[1]), fmaxf(sred[2], sred[3]));
    float ssum = 0.f;
    for (int v = threadIdx.x; v < NVOC; v += 256) ssum += expf(lg[v] - mx);
    for (int off = 32; off; off >>= 1) ssum += __shfl_down(ssum, off);
    __shared__ float sred2[4];
    if ((threadIdx.x & 63) == 0) sred2[threadIdx.x >> 6] = ssum;
    __syncthreads();
    ssum = sred2[0] + sred2[1] + sred2[2] + sred2[3];
    float inv = 1.f / ssum;
    for (int v = threadIdx.x; v < NVOC; v += 256) out[v] = expf(lg[v] - mx) * inv;
}

extern "C" void kernel_launch(void* const* d_in, const int* in_sizes, int n_in,
                              void* d_out, int out_size, void* d_ws, size_t ws_size,
                              hipStream_t stream) {
    const float* im = (const float*)d_in[0];
    const int* w_in = (const int*)d_in[1];
    const int* cap = (const int*)d_in[2];
    const float* emb = (const float*)d_in[3];
    const float* W_enc = (const float*)d_in[4];
    const float* b_enc = (const float*)d_in[5];
    const float* W_glob = (const float*)d_in[6];
    const float* b_glob = (const float*)d_in[7];
    const float* W_ih = (const float*)d_in[8];
    const float* b_ih = (const float*)d_in[9];
    const float* W_hh = (const float*)d_in[10];
    const float* b_hh = (const float*)d_in[11];
    const float* W_xg = (const float*)d_in[12];
    const float* b_xg = (const float*)d_in[13];
    const float* W_hg = (const float*)d_in[14];
    const float* b_hg = (const float*)d_in[15];
    const float* Wv = (const float*)d_in[16];
    const float* bv = (const float*)d_in[17];
    const float* Ws = (const float*)d_in[18];
    const float* bs = (const float*)d_in[19];
    const float* Wh = (const float*)d_in[20];
    const float* bh = (const float*)d_in[21];
    const float* wa = (const float*)d_in[22];
    // const float* ba = (const float*)d_in[23];  // cancels in softmax(65)
    const float* W_out = (const float*)d_in[24];
    const float* b_out = (const float*)d_in[25];

    float* out = (float*)d_out;
    float* pred = out;                                   // 128*30*10000
    float* out_target = out + (size_t)NB * NT * NVOC;    // 128*30
    float* out_lens = out_target + NB * NT;              // 128

    // ---- workspace carve-up ----
    char* p = (char*)d_ws;
    size_t off = 0;
    auto carve = [&](size_t bytes) {
        void* r = p + off;
        off += (bytes + 255) & ~(size_t)255;
        return r;
    };
    int* order = (int*)carve(NB * sizeof(int));
    int* lens_s = (int*)carve(NB * sizeof(int));
    float* meanim = (float*)carve((size_t)NB * ND * 4);
    float* g = (float*)carve((size_t)NB * NEM * 4);
    float* V = (float*)carve((size_t)NB * NKK * NH * 4);
    float* VA = (float*)carve((size_t)NB * NKK * NA * 4);
    float* xbuf = (float*)carve((size_t)NB * 2048 * 4);
    float* gates = (float*)carve((size_t)NB * 4 * NH * 4);
    float* sg_pre = (float*)carve((size_t)NB * NH * 4);
    float* h = (float*)carve((size_t)NB * NH * 4);
    float* c = (float*)carve((size_t)NB * NH * 4);
    float* s = (float*)carve((size_t)NB * NH * 4);
    float* hp = (float*)carve((size_t)NB * NA * 4);
    float* sws = (float*)carve((size_t)NB * NA * 4);
    float* zbuf = (float*)carve((size_t)NB * NH * 4);
    float* logits = (float*)carve((size_t)NB * NVOC * 4);
    float* bgates = (float*)carve(4 * NH * 4);
    float* bsg = (float*)carve(NH * 4);
    if (off > ws_size) return;  // workspace too small — fail loudly via absmax

    // ---- one-time per call ----
    sort_kernel<<<1, NB, 0, stream>>>(cap, w_in, out_target, out_lens, order, lens_s);
    init_kernel<<<(NB * NH) / 256, 256, 0, stream>>>(b_ih, b_hh, b_xg, b_hg, bgates, bsg, h, c);
    meanim_kernel<<<NB, 256, 0, stream>>>(im, order, meanim);
    // g = relu(meanim @ W_glob + b_glob)            (128 x 512, K=1536)
    gemm_f32<<<dim3(NEM / 64, NB / 64), 256, 0, stream>>>(
        meanim, W_glob, nullptr, 0, b_glob, g, NB, NEM, ND, ND, NEM, NEM, nullptr, 1, 1);
    // V = relu(im[order] @ W_enc + b_enc)           (8192 x 1024, K=1536)
    gemm_f32<<<dim3(NH / 64, (NB * NKK) / 64), 256, 0, stream>>>(
        im, W_enc, nullptr, 0, b_enc, V, NB * NKK, NH, ND, ND, NH, NH, order, NKK, 1);
    // VA = V @ Wv + bv                              (8192 x 1024, K=1024)
    gemm_f32<<<dim3(NA / 64, (NB * NKK) / 64), 256, 0, stream>>>(
        V, Wv, nullptr, 0, bv, VA, NB * NKK, NA, NH, NH, NA, NA, nullptr, 1, 0);

    // ---- 30 sequential timesteps ----
    for (int t = 0; t < NT; t++) {
        gather_x<<<NB, 256, 0, stream>>>(emb, g, h, w_in, order, t, xbuf);
        // gates = x@W_ih + h@W_hh + (b_ih+b_hh)     (128 x 4096, K=2048 split)
        gemm_f32<<<dim3(4 * NH / 64, NB / 64), 256, 0, stream>>>(
            xbuf, W_ih, W_hh, 2 * NEM, bgates, gates, NB, 4 * NH, 2048, 2048, 4 * NH, 4 * NH,
            nullptr, 1, 0);
        // sg_pre = x@W_xg + h@W_hg + (b_xg+b_hg)    (128 x 1024, K=2048 split)
        gemm_f32<<<dim3(NH / 64, NB / 64), 256, 0, stream>>>(
            xbuf, W_xg, W_hg, 2 * NEM, bsg, sg_pre, NB, NH, 2048, 2048, NH, NH, nullptr, 1, 0);
        lstm_pointwise<<<(NB * NH) / 256, 256, 0, stream>>>(gates, sg_pre, c, h, s);
        // hp = h_new @ Wh + bh                      (128 x 1024, K=1024)
        gemm_f32<<<dim3(NA / 64, NB / 64), 256, 0, stream>>>(
            h, Wh, nullptr, 0, bh, hp, NB, NA, NH, NH, NA, NA, nullptr, 1, 0);
        // sws = s @ Ws + bs                         (128 x 1024, K=1024)
        gemm_f32<<<dim3(NA / 64, NB / 64), 256, 0, stream>>>(
            s, Ws, nullptr, 0, bs, sws, NB, NA, NH, NH, NA, NA, nullptr, 1, 0);
        attn_kernel<<<NB, 256, 0, stream>>>(VA, V, hp, sws, wa, s, h, zbuf);
        // logits = z_t @ W_out + b_out              (128 x 10000, K=1024)
        gemm_f32<<<dim3((NVOC + 63) / 64, NB / 64), 256, 0, stream>>>(
            zbuf, W_out, nullptr, 0, b_out, logits, NB, NVOC, NH, NH, NVOC, NVOC, nullptr, 1, 0);
        vocab_softmax<<<NB, 256, 0, stream>>>(logits, lens_s, t, pred);
    }
}

// Round 2
// 7154.016 us; speedup vs baseline: 3.0315x; 3.0315x over previous
//
#include <hip/hip_runtime.h>
#include <math.h>

#define NB 128
#define NKK 64
#define ND 1536
#define NEM 512
#define NH 1024
#define NVOC 10000
#define NT 30

typedef __bf16 bf16x8 __attribute__((ext_vector_type(8)));
typedef __bf16 bf16x4 __attribute__((ext_vector_type(4)));
typedef float f32x4 __attribute__((ext_vector_type(4)));

__device__ __forceinline__ float sigf(float x) { return 1.0f / (1.0f + expf(-x)); }

// ---------------- sort + target/lens + widx ----------------
__global__ void sort_kernel(const int* __restrict__ cap, const int* __restrict__ w,
                            float* __restrict__ out_target, float* __restrict__ out_lens,
                            int* __restrict__ order, int* __restrict__ lens_s,
                            int* __restrict__ widx) {
    __shared__ int lcap[NB];
    __shared__ int sord[NB];
    int b = threadIdx.x;
    lcap[b] = cap[b];
    __syncthreads();
    int lb = lcap[b];
    int pos = 0;
    for (int j = 0; j < NB; j++) {
        int lj = lcap[j];
        if (lj > lb || (lj == lb && j < b)) pos++;
    }
    sord[pos] = b;
    __syncthreads();
    int src = sord[b];
    order[b] = src;
    int ln = lcap[src] - 1;
    lens_s[b] = ln;
    out_lens[b] = (float)ln;
    for (int j = 0; j < NT; j++)
        out_target[b * NT + j] = (float)w[src * (NT + 1) + j + 1];
    for (int t = 0; t < NT; t++)
        widx[t * NB + b] = w[src * (NT + 1) + t];
}

// ---------------- init h, c ----------------
__global__ void init_kernel(float* __restrict__ h, float* __restrict__ c) {
    int tid = blockIdx.x * 256 + threadIdx.x;
    h[tid] = 0.f; c[tid] = 0.f;
}

// ---------------- mean over K (sorted order), f32 out ----------------
__global__ void meanim_kernel(const float* __restrict__ im, const int* __restrict__ order,
                              float* __restrict__ meanim) {
    int b = blockIdx.x;
    int src = order[b];
    const float* base = im + (size_t)src * NKK * ND;
    for (int d = threadIdx.x; d < ND; d += 256) {
        float acc = 0.f;
        for (int k = 0; k < NKK; k++) acc += base[(size_t)k * ND + d];
        meanim[b * ND + d] = acc * (1.0f / NKK);
    }
}

// ---------------- weight packing ----------------
// Wstep (2048 x 5120): rows 0..1023 = [W_ih | W_xg], rows 1024..2047 = [W_hh | W_hg]
__global__ void pack_step(const float* __restrict__ W_ih, const float* __restrict__ W_hh,
                          const float* __restrict__ W_xg, const float* __restrict__ W_hg,
                          const float* __restrict__ b_ih, const float* __restrict__ b_hh,
                          const float* __restrict__ b_xg, const float* __restrict__ b_hg,
                          __bf16* __restrict__ Wstep, float* __restrict__ bstep) {
    int n = blockIdx.x * 256 + threadIdx.x;   // 0..5119
    int r = blockIdx.y;                       // 0..2047
    float v;
    if (r < 1024) v = (n < 4096) ? W_ih[(size_t)r * 4096 + n] : W_xg[(size_t)r * 1024 + (n - 4096)];
    else {
        int rr = r - 1024;
        v = (n < 4096) ? W_hh[(size_t)rr * 4096 + n] : W_hg[(size_t)rr * 1024 + (n - 4096)];
    }
    Wstep[(size_t)r * 5120 + n] = (__bf16)v;
    if (r == 0) bstep[n] = (n < 4096) ? (b_ih[n] + b_hh[n]) : (b_xg[n - 4096] + b_hg[n - 4096]);
}

// W2 (2 x 1024 x 1024) = [Wh, Ws]; b2 (2 x 1024) = [bh, bs]
__global__ void pack_w2(const float* __restrict__ Wh, const float* __restrict__ Ws,
                        const float* __restrict__ bh, const float* __restrict__ bs,
                        __bf16* __restrict__ W2, float* __restrict__ b2) {
    int n = blockIdx.x * 256 + threadIdx.x;   // 0..1023
    int r = blockIdx.y;                       // 0..1023
    int z = blockIdx.z;                       // 0..1
    const float* W = z ? Ws : Wh;
    W2[(size_t)z * 1024 * 1024 + (size_t)r * 1024 + n] = (__bf16)W[(size_t)r * 1024 + n];
    if (r == 0) b2[z * 1024 + n] = z ? bs[n] : bh[n];
}

__global__ void conv_bf16(const float* __restrict__ src, __bf16* __restrict__ dst, int n) {
    int id = blockIdx.x * 256 + threadIdx.x;
    if (id < n) dst[id] = (__bf16)src[id];
}

// ---------------- MFMA GEMM ----------------
// C(MxN) = A(MxK) @ B(KxN) + bias, optional relu, f32 or bf16 out.
// AMODE: 0 = f32 A direct; 1 = x-concat [emb|g|h] (f32 sources, M=128);
//        2 = f32 A with 64-row-group permutation via order; 3 = bf16 A direct.
// BF32: B is f32 (convert in staging), else bf16.
#define BM 128
#define BN 64
#define BK 32

template <int AMODE, bool BF32, bool RELU, bool OUTBF>
__global__ __launch_bounds__(256) void mfma_gemm(
    const void* __restrict__ Aptr, int lda,
    const void* __restrict__ Bptr, int ldb,
    const float* __restrict__ bias,
    void* __restrict__ Cptr, int ldc,
    int M, int N, int K,
    size_t strideA, size_t strideB, size_t strideBias, size_t strideC,
    const float* __restrict__ embp, const float* __restrict__ gp, const float* __restrict__ hp,
    const int* __restrict__ widx, const int* __restrict__ order) {
    const int tid = threadIdx.x;
    const int lane = tid & 63;
    const int wid = tid >> 6;
    const int wr = wid >> 1, wc = wid & 1;
    const int m0 = blockIdx.y * BM;
    const int n0 = blockIdx.x * BN;
    const int z = blockIdx.z;
    const int lr = lane & 15, lg = lane >> 4;

    __shared__ __bf16 As[BM][40];      // [row][k]
    __shared__ __bf16 Bs[BN][40];      // transposed: [col][k]

    f32x4 acc[4][2];
#pragma unroll
    for (int i = 0; i < 4; i++)
#pragma unroll
        for (int j = 0; j < 2; j++) acc[i][j] = (f32x4){0.f, 0.f, 0.f, 0.f};

    // A staging role: thread -> (row ar, 16-elem half ah)
    const int ar = tid >> 1;
    const int ah = (tid & 1) * 16;
    // B staging role (tid < 64): 4 k-rows x 8 cols
    const int bkq = tid >> 3;           // 0..7 (valid when tid<64)
    const int bc0 = (tid & 7) * 8;

    // Per-row A base pointers
    const float* af_base = nullptr;
    const __bf16* ab_base = nullptr;
    if (AMODE == 0) af_base = (const float*)Aptr + z * strideA + (size_t)(m0 + ar) * lda;
    if (AMODE == 2) {
        int gr = m0 + ar;
        int srow = order[gr >> 6] * 64 + (gr & 63);
        af_base = (const float*)Aptr + (size_t)srow * lda;
    }
    if (AMODE == 3) ab_base = (const __bf16*)Aptr + z * strideA + (size_t)(m0 + ar) * lda;
    int wid_b = 0;
    if (AMODE == 1) wid_b = widx[ar];

    const __bf16* Bb = nullptr;
    const float* Bf = nullptr;
    if (BF32) Bf = (const float*)Bptr + z * strideB;
    else Bb = (const __bf16*)Bptr + z * strideB;

    for (int k0 = 0; k0 < K; k0 += BK) {
        // ---- stage A ----
        if (AMODE == 3) {
            const bf16x8* s8 = (const bf16x8*)(ab_base + k0 + ah);
            *(bf16x8*)&As[ar][ah] = s8[0];
            *(bf16x8*)&As[ar][ah + 8] = s8[1];
        } else {
            const float* src;
            if (AMODE == 1) {
                int kk = k0 + ah;
                if (kk < 512) src = embp + (size_t)wid_b * 512 + kk;
                else if (kk < 1024) src = gp + (size_t)ar * 512 + (kk - 512);
                else src = hp + (size_t)ar * 1024 + (kk - 1024);
            } else {
                src = af_base + k0 + ah;
            }
            float4 f0 = *(const float4*)(src);
            float4 f1 = *(const float4*)(src + 4);
            float4 f2 = *(const float4*)(src + 8);
            float4 f3 = *(const float4*)(src + 12);
            bf16x8 v0 = {(__bf16)f0.x, (__bf16)f0.y, (__bf16)f0.z, (__bf16)f0.w,
                         (__bf16)f1.x, (__bf16)f1.y, (__bf16)f1.z, (__bf16)f1.w};
            bf16x8 v1 = {(__bf16)f2.x, (__bf16)f2.y, (__bf16)f2.z, (__bf16)f2.w,
                         (__bf16)f3.x, (__bf16)f3.y, (__bf16)f3.z, (__bf16)f3.w};
            *(bf16x8*)&As[ar][ah] = v0;
            *(bf16x8*)&As[ar][ah + 8] = v1;
        }
        // ---- stage B (transposed) ----
        if (tid < 64) {
            bf16x8 r0, r1, r2, r3;
            bool nok = (n0 + bc0) < N;
            int krow = k0 + bkq * 4;
            if (BF32) {
                if (nok) {
#pragma unroll
                    for (int q = 0; q < 4; q++) {
                        const float* bp = Bf + (size_t)(krow + q) * ldb + n0 + bc0;
                        float4 g0 = *(const float4*)(bp);
                        float4 g1 = *(const float4*)(bp + 4);
                        bf16x8 rv = {(__bf16)g0.x, (__bf16)g0.y, (__bf16)g0.z, (__bf16)g0.w,
                                     (__bf16)g1.x, (__bf16)g1.y, (__bf16)g1.z, (__bf16)g1.w};
                        if (q == 0) r0 = rv; else if (q == 1) r1 = rv; else if (q == 2) r2 = rv; else r3 = rv;
                    }
                } else {
                    bf16x8 zv = {};
                    r0 = r1 = r2 = r3 = zv;
                }
            } else {
                if (nok) {
                    r0 = *(const bf16x8*)(Bb + (size_t)(krow + 0) * ldb + n0 + bc0);
                    r1 = *(const bf16x8*)(Bb + (size_t)(krow + 1) * ldb + n0 + bc0);
                    r2 = *(const bf16x8*)(Bb + (size_t)(krow + 2) * ldb + n0 + bc0);
                    r3 = *(const bf16x8*)(Bb + (size_t)(krow + 3) * ldb + n0 + bc0);
                } else {
                    bf16x8 zv = {};
                    r0 = r1 = r2 = r3 = zv;
                }
            }
#pragma unroll
            for (int j = 0; j < 8; j++) {
                bf16x4 qv = {r0[j], r1[j], r2[j], r3[j]};
                *(bf16x4*)&Bs[bc0 + j][bkq * 4] = qv;
            }
        }
        __syncthreads();
        // ---- compute ----
        bf16x8 afr[4];
#pragma unroll
        for (int mi = 0; mi < 4; mi++)
            afr[mi] = *(const bf16x8*)&As[wr * 64 + mi * 16 + lr][lg * 8];
        bf16x8 bfr[2];
#pragma unroll
        for (int ni = 0; ni < 2; ni++)
            bfr[ni] = *(const bf16x8*)&Bs[wc * 32 + ni * 16 + lr][lg * 8];
#pragma unroll
        for (int mi = 0; mi < 4; mi++)
#pragma unroll
            for (int ni = 0; ni < 2; ni++)
                acc[mi][ni] = __builtin_amdgcn_mfma_f32_16x16x32_bf16(afr[mi], bfr[ni], acc[mi][ni], 0, 0, 0);
        __syncthreads();
    }

    // ---- epilogue ----
    const float* bias_z = bias + z * strideBias;
    float* Cf = (float*)Cptr + z * strideC;
    __bf16* Cb = (__bf16*)Cptr + z * strideC;
#pragma unroll
    for (int mi = 0; mi < 4; mi++) {
#pragma unroll
        for (int ni = 0; ni < 2; ni++) {
#pragma unroll
            for (int rr = 0; rr < 4; rr++) {
                int row = m0 + wr * 64 + mi * 16 + lg * 4 + rr;
                int col = n0 + wc * 32 + ni * 16 + lr;
                if (col < N) {
                    float v = acc[mi][ni][rr] + bias_z[col];
                    if (RELU) v = fmaxf(v, 0.f);
                    if (OUTBF) Cb[(size_t)row * ldc + col] = (__bf16)v;
                    else Cf[(size_t)row * ldc + col] = v;
                }
            }
        }
    }
}

// ---------------- LSTM pointwise ----------------
__global__ void lstm_pointwise(const float* __restrict__ gates, float* __restrict__ c,
                               float* __restrict__ h, float* __restrict__ s) {
    int tid = blockIdx.x * 256 + threadIdx.x;   // b*NH + j
    int b = tid >> 10, j = tid & 1023;
    const float* gr = gates + (size_t)b * 5120;
    float ig = sigf(gr[j]);
    float fg = sigf(gr[1024 + j]);
    float gg = tanhf(gr[2048 + j]);
    float og = sigf(gr[3072 + j]);
    float sgg = sigf(gr[4096 + j]);
    float cn = fg * c[tid] + ig * gg;
    float tc = tanhf(cn);
    c[tid] = cn;
    h[tid] = og * tc;
    s[tid] = sgg * tc;
}

// ---------------- attention ----------------
__global__ __launch_bounds__(256) void attn_kernel(
    const __bf16* __restrict__ VA, const __bf16* __restrict__ V,
    const float* __restrict__ hp, const float* __restrict__ sws,
    const float* __restrict__ wa, const float* __restrict__ s,
    const float* __restrict__ h, __bf16* __restrict__ z) {
    __shared__ float zscore[NKK + 1];
    __shared__ float alpha_s[NKK + 1];
    int b = blockIdx.x;
    int wave = threadIdx.x >> 6, lane = threadIdx.x & 63;

    // per-lane registers: hp/wa chunk (a = lane*16 + j)
    float hp_reg[16], wa_reg[16];
    {
        const float* hb = hp + (size_t)b * NH + lane * 16;
        const float* wb = wa + lane * 16;
#pragma unroll
        for (int q = 0; q < 4; q++) {
            float4 hv = *(const float4*)(hb + q * 4);
            float4 wv = *(const float4*)(wb + q * 4);
            hp_reg[q * 4 + 0] = hv.x; hp_reg[q * 4 + 1] = hv.y;
            hp_reg[q * 4 + 2] = hv.z; hp_reg[q * 4 + 3] = hv.w;
            wa_reg[q * 4 + 0] = wv.x; wa_reg[q * 4 + 1] = wv.y;
            wa_reg[q * 4 + 2] = wv.z; wa_reg[q * 4 + 3] = wv.w;
        }
    }
    for (int k = wave; k <= NKK; k += 4) {
        float p = 0.f;
        if (k < NKK) {
            const bf16x8* row = (const bf16x8*)(VA + ((size_t)(b * NKK + k)) * NH + lane * 16);
            bf16x8 v0 = row[0], v1 = row[1];
#pragma unroll
            for (int j = 0; j < 8; j++) {
                p += tanhf((float)v0[j] + hp_reg[j]) * wa_reg[j];
                p += tanhf((float)v1[j] + hp_reg[8 + j]) * wa_reg[8 + j];
            }
        } else {
            const float* sp = sws + (size_t)b * NH + lane * 16;
#pragma unroll
            for (int j = 0; j < 16; j++) p += tanhf(sp[j] + hp_reg[j]) * wa_reg[j];
        }
        for (int off = 32; off; off >>= 1) p += __shfl_down(p, off);
        if (lane == 0) zscore[k] = p;
    }
    __syncthreads();
    if (threadIdx.x == 0) {
        float mx = zscore[0];
        for (int i = 1; i <= NKK; i++) mx = fmaxf(mx, zscore[i]);
        float ssum = 0.f;
        for (int i = 0; i <= NKK; i++) { float e = expf(zscore[i] - mx); alpha_s[i] = e; ssum += e; }
        float inv = 1.f / ssum;
        for (int i = 0; i <= NKK; i++) alpha_s[i] *= inv;
    }
    __syncthreads();
    float beta = alpha_s[NKK];
    for (int jj = threadIdx.x; jj < NH; jj += 256) {
        float ctx = 0.f;
        const __bf16* vp = V + ((size_t)b * NKK) * NH + jj;
#pragma unroll 8
        for (int k = 0; k < NKK; k++) ctx += alpha_s[k] * (float)vp[(size_t)k * NH];
        float zv = beta * s[b * NH + jj] + (1.f - beta) * ctx + h[b * NH + jj];
        z[b * NH + jj] = (__bf16)zv;
    }
}

// ---------------- vocab softmax + mask ----------------
__global__ __launch_bounds__(256) void vocab_softmax(const float* __restrict__ logits,
                                                     const int* __restrict__ lens_s, int t,
                                                     float* __restrict__ pred) {
    int b = blockIdx.x;
    float* out = pred + (size_t)b * NT * NVOC + (size_t)t * NVOC;
    if (t >= lens_s[b]) {
        for (int v = threadIdx.x; v < NVOC; v += 256) out[v] = 0.f;
        return;
    }
    const float* lg = logits + (size_t)b * NVOC;
    float mx = -1e30f;
    for (int v = threadIdx.x; v < NVOC; v += 256) mx = fmaxf(mx, lg[v]);
    __shared__ float sred[4];
    for (int off = 32; off; off >>= 1) mx = fmaxf(mx, __shfl_down(mx, off));
    if ((threadIdx.x & 63) == 0) sred[threadIdx.x >> 6] = mx;
    __syncthreads();
    mx = fmaxf(fmaxf(sred[0], sred[1]), fmaxf(sred[2], sred[3]));
    float ssum = 0.f;
    for (int v = threadIdx.x; v < NVOC; v += 256) ssum += expf(lg[v] - mx);
    for (int off = 32; off; off >>= 1) ssum += __shfl_down(ssum, off);
    __shared__ float sred2[4];
    if ((threadIdx.x & 63) == 0) sred2[threadIdx.x >> 6] = ssum;
    __syncthreads();
    ssum = sred2[0] + sred2[1] + sred2[2] + sred2[3];
    float inv = 1.f / ssum;
    for (int v = threadIdx.x; v < NVOC; v += 256) out[v] = expf(lg[v] - mx) * inv;
}

extern "C" void kernel_launch(void* const* d_in, const int* in_sizes, int n_in,
                              void* d_out, int out_size, void* d_ws, size_t ws_size,
                              hipStream_t stream) {
    const float* im = (const float*)d_in[0];
    const int* w_in = (const int*)d_in[1];
    const int* cap = (const int*)d_in[2];
    const float* emb = (const float*)d_in[3];
    const float* W_enc = (const float*)d_in[4];
    const float* b_enc = (const float*)d_in[5];
    const float* W_glob = (const float*)d_in[6];
    const float* b_glob = (const float*)d_in[7];
    const float* W_ih = (const float*)d_in[8];
    const float* b_ih = (const float*)d_in[9];
    const float* W_hh = (const float*)d_in[10];
    const float* b_hh = (const float*)d_in[11];
    const float* W_xg = (const float*)d_in[12];
    const float* b_xg = (const float*)d_in[13];
    const float* W_hg = (const float*)d_in[14];
    const float* b_hg = (const float*)d_in[15];
    const float* Wv = (const float*)d_in[16];
    const float* bv = (const float*)d_in[17];
    const float* Ws = (const float*)d_in[18];
    const float* bs = (const float*)d_in[19];
    const float* Wh = (const float*)d_in[20];
    const float* bh = (const float*)d_in[21];
    const float* wa = (const float*)d_in[22];
    // ba cancels in softmax(65)
    const float* W_out = (const float*)d_in[24];
    const float* b_out = (const float*)d_in[25];

    float* out = (float*)d_out;
    float* pred = out;
    float* out_target = out + (size_t)NB * NT * NVOC;
    float* out_lens = out_target + NB * NT;

    char* p = (char*)d_ws;
    size_t off = 0;
    auto carve = [&](size_t bytes) {
        void* r = p + off;
        off += (bytes + 255) & ~(size_t)255;
        return r;
    };
    int* order = (int*)carve(NB * 4);
    int* lens_s = (int*)carve(NB * 4);
    int* widx = (int*)carve(NT * NB * 4);
    __bf16* Wstep = (__bf16*)carve((size_t)2048 * 5120 * 2);
    float* bstep = (float*)carve(5120 * 4);
    __bf16* W2 = (__bf16*)carve((size_t)2 * 1024 * 1024 * 2);
    float* b2 = (float*)carve(2 * 1024 * 4);
    __bf16* Wout_bf = (__bf16*)carve((size_t)1024 * 10000 * 2);
    __bf16* V_bf = (__bf16*)carve((size_t)NB * NKK * NH * 2);
    __bf16* VA_bf = (__bf16*)carve((size_t)NB * NKK * NH * 2);
    float* meanim = (float*)carve((size_t)NB * ND * 4);
    float* g = (float*)carve((size_t)NB * NEM * 4);
    float* gates = (float*)carve((size_t)NB * 5120 * 4);
    float* hs = (float*)carve((size_t)2 * NB * NH * 4);   // [h ; s]
    float* c = (float*)carve((size_t)NB * NH * 4);
    float* hpsws = (float*)carve((size_t)2 * NB * NH * 4); // [hp ; sws]
    __bf16* z_bf = (__bf16*)carve((size_t)NB * NH * 2);
    float* logits = (float*)carve((size_t)NB * NVOC * 4);
    if (off > ws_size) return;  // fail loudly via absmax if ws too small

    float* h = hs;
    float* s = hs + (size_t)NB * NH;
    float* hp = hpsws;
    float* sws = hpsws + (size_t)NB * NH;

    // ---- one-time ----
    sort_kernel<<<1, NB, 0, stream>>>(cap, w_in, out_target, out_lens, order, lens_s, widx);
    init_kernel<<<(NB * NH) / 256, 256, 0, stream>>>(h, c);
    meanim_kernel<<<NB, 256, 0, stream>>>(im, order, meanim);
    pack_step<<<dim3(20, 2048), 256, 0, stream>>>(W_ih, W_hh, W_xg, W_hg, b_ih, b_hh, b_xg, b_hg,
                                                  Wstep, bstep);
    pack_w2<<<dim3(4, 1024, 2), 256, 0, stream>>>(Wh, Ws, bh, bs, W2, b2);
    conv_bf16<<<(1024 * 10000) / 256, 256, 0, stream>>>(W_out, Wout_bf, 1024 * 10000);

    // g = relu(meanim @ W_glob + b_glob)   (128 x 512, K=1536), f32 out
    mfma_gemm<0, true, true, false><<<dim3(NEM / BN, NB / BM), 256, 0, stream>>>(
        meanim, ND, W_glob, NEM, b_glob, g, NEM, NB, NEM, ND, 0, 0, 0, 0,
        nullptr, nullptr, nullptr, nullptr, nullptr);
    // V = relu(im[order] @ W_enc + b_enc)  (8192 x 1024, K=1536), bf16 out
    mfma_gemm<2, true, true, true><<<dim3(NH / BN, (NB * NKK) / BM), 256, 0, stream>>>(
        im, ND, W_enc, NH, b_enc, V_bf, NH, NB * NKK, NH, ND, 0, 0, 0, 0,
        nullptr, nullptr, nullptr, nullptr, order);
    // VA = V @ Wv + bv                     (8192 x 1024, K=1024), bf16 out
    mfma_gemm<3, true, false, true><<<dim3(NH / BN, (NB * NKK) / BM), 256, 0, stream>>>(
        V_bf, NH, Wv, NH, bv, VA_bf, NH, NB * NKK, NH, NH, 0, 0, 0, 0,
        nullptr, nullptr, nullptr, nullptr, nullptr);

    // ---- 30 timesteps ----
    for (int t = 0; t < NT; t++) {
        // gates|sg = [emb|g|h] @ Wstep + bstep   (128 x 5120, K=2048)
        mfma_gemm<1, false, false, false><<<dim3(5120 / BN, 1), 256, 0, stream>>>(
            nullptr, 0, Wstep, 5120, bstep, gates, 5120, NB, 5120, 2048, 0, 0, 0, 0,
            emb, g, h, widx + t * NB, nullptr);
        lstm_pointwise<<<(NB * NH) / 256, 256, 0, stream>>>(gates, c, h, s);
        // [hp ; sws] = [h ; s] @ [Wh ; Ws] + [bh ; bs]   (z-batched)
        mfma_gemm<0, false, false, false><<<dim3(NH / BN, 1, 2), 256, 0, stream>>>(
            hs, NH, W2, NH, b2, hpsws, NH, NB, NH, NH,
            (size_t)NB * NH, (size_t)NH * NH, (size_t)NH, (size_t)NB * NH,
            nullptr, nullptr, nullptr, nullptr, nullptr);
        attn_kernel<<<NB, 256, 0, stream>>>(VA_bf, V_bf, hp, sws, wa, s, h, z_bf);
        // logits = z @ W_out + b_out        (128 x 10000, K=1024)
        mfma_gemm<3, false, false, false><<<dim3((NVOC + BN - 1) / BN, 1), 256, 0, stream>>>(
            z_bf, NH, Wout_bf, NVOC, b_out, logits, NVOC, NB, NVOC, NH, 0, 0, 0, 0,
            nullptr, nullptr, nullptr, nullptr, nullptr);
        vocab_softmax<<<NB, 256, 0, stream>>>(logits, lens_s, t, pred);
    }
}

// Round 3
// 4212.268 us; speedup vs baseline: 5.1486x; 1.6984x over previous
//
#include <hip/hip_runtime.h>
#include <math.h>

#define NB 128
#define NKK 64
#define ND 1536
#define NEM 512
#define NH 1024
#define NVOC 10000
#define NT 30

typedef __bf16 bf16x8 __attribute__((ext_vector_type(8)));
typedef float f32x4 __attribute__((ext_vector_type(4)));

__device__ __forceinline__ float sigf(float x) { return 1.0f / (1.0f + expf(-x)); }

// ---------------- sort + target/lens + widx ----------------
__global__ void sort_kernel(const int* __restrict__ cap, const int* __restrict__ w,
                            float* __restrict__ out_target, float* __restrict__ out_lens,
                            int* __restrict__ order, int* __restrict__ lens_s,
                            int* __restrict__ widx) {
    __shared__ int lcap[NB];
    __shared__ int sord[NB];
    int b = threadIdx.x;
    lcap[b] = cap[b];
    __syncthreads();
    int lb = lcap[b];
    int pos = 0;
    for (int j = 0; j < NB; j++) {
        int lj = lcap[j];
        if (lj > lb || (lj == lb && j < b)) pos++;
    }
    sord[pos] = b;
    __syncthreads();
    int src = sord[b];
    order[b] = src;
    int ln = lcap[src] - 1;
    lens_s[b] = ln;
    out_lens[b] = (float)ln;
    for (int j = 0; j < NT; j++)
        out_target[b * NT + j] = (float)w[src * (NT + 1) + j + 1];
    for (int t = 0; t < NT; t++)
        widx[t * NB + b] = w[src * (NT + 1) + t];
}

// ---------------- init h_bf, c ----------------
__global__ void init_kernel(__bf16* __restrict__ h, float* __restrict__ c) {
    int tid = blockIdx.x * 256 + threadIdx.x;
    h[tid] = (__bf16)0.f;
    c[tid] = 0.f;
}

// ---------------- mean over K (sorted order), bf16 out ----------------
__global__ void meanim_kernel(const float* __restrict__ im, const int* __restrict__ order,
                              __bf16* __restrict__ meanb) {
    int b = blockIdx.x;
    int src = order[b];
    const float* base = im + (size_t)src * NKK * ND;
    for (int d = threadIdx.x; d < ND; d += 256) {
        float acc = 0.f;
        for (int k = 0; k < NKK; k++) acc += base[(size_t)k * ND + d];
        meanb[b * ND + d] = (__bf16)(acc * (1.0f / NKK));
    }
}

// ---------------- LDS-tiled transpose + f32->bf16 pack: dst[n][k] = src[k][n] ----------------
__global__ __launch_bounds__(256) void transpose_pack(
    const float* __restrict__ src, int ldn, int K, int N,
    __bf16* __restrict__ dst, int ldk) {
    __shared__ float tile[64][65];
    int k0 = blockIdx.y * 64, n0 = blockIdx.x * 64;
    int t = threadIdx.x;
    int kr = t >> 2, nc0 = (t & 3) * 16;
    int kk = k0 + kr;
#pragma unroll
    for (int j = 0; j < 16; j += 4) {
        int nn = n0 + nc0 + j;
        float4 v = make_float4(0.f, 0.f, 0.f, 0.f);
        if (kk < K && nn + 3 < N) v = *(const float4*)(src + (size_t)kk * ldn + nn);
        else if (kk < K) {
            float tmp[4] = {0.f, 0.f, 0.f, 0.f};
            for (int q = 0; q < 4; q++) if (nn + q < N) tmp[q] = src[(size_t)kk * ldn + nn + q];
            v = make_float4(tmp[0], tmp[1], tmp[2], tmp[3]);
        }
        tile[kr][nc0 + j + 0] = v.x; tile[kr][nc0 + j + 1] = v.y;
        tile[kr][nc0 + j + 2] = v.z; tile[kr][nc0 + j + 3] = v.w;
    }
    __syncthreads();
    int nr = t >> 2, kc0 = (t & 3) * 16;
    if (n0 + nr < N) {
        __bf16* drow = dst + (size_t)(n0 + nr) * ldk + k0 + kc0;
#pragma unroll
        for (int j = 0; j < 16; j++)
            if (k0 + kc0 + j < K) drow[j] = (__bf16)tile[kc0 + j][nr];
    }
}

// ---------------- f32 -> bf16 vector convert ----------------
__global__ void conv_bf16_vec(const float* __restrict__ src, __bf16* __restrict__ dst, int n4) {
    int id = blockIdx.x * 256 + threadIdx.x;
    if (id < n4) {
        float4 v = *(const float4*)(src + (size_t)id * 4);
        __bf16* d = dst + (size_t)id * 4;
        d[0] = (__bf16)v.x; d[1] = (__bf16)v.y; d[2] = (__bf16)v.z; d[3] = (__bf16)v.w;
    }
}

// ---------------- bias packs ----------------
__global__ void pack_biases(const float* __restrict__ b_ih, const float* __restrict__ b_hh,
                            const float* __restrict__ b_xg, const float* __restrict__ b_hg,
                            const float* __restrict__ bh, const float* __restrict__ bs,
                            float* __restrict__ bstep, float* __restrict__ b2) {
    int i = blockIdx.x * 256 + threadIdx.x;   // 0..5119
    if (i < 4096) bstep[i] = b_ih[i] + b_hh[i];
    else bstep[i] = b_xg[i - 4096] + b_hg[i - 4096];
    if (i < 1024) b2[i] = bh[i];
    else if (i < 2048) b2[i] = bs[i - 1024];
}

// ---------------- MFMA GEMM, Bt = [N][K] bf16 ----------------
// AMODE: 0 = bf16 A [M][K]; 1 = x-concat [emb|g|h] (bf16 sources, M=128);
//        2 = f32 A with 64-row-group permutation via order.
#define BM 128
#define BN 64
#define BK 64

template <int AMODE, bool RELU, bool OUTBF>
__global__ __launch_bounds__(256) void gemm_bt(
    const void* __restrict__ Aptr, int lda,
    const __bf16* __restrict__ Bt, int ldb,
    const float* __restrict__ bias,
    void* __restrict__ Cptr, int ldc,
    int M, int N, int K,
    size_t strideA, size_t strideB, size_t strideBias, size_t strideC,
    const __bf16* __restrict__ embb, const __bf16* __restrict__ gb,
    const __bf16* __restrict__ hb, const int* __restrict__ widx_t,
    const int* __restrict__ order) {
    const int t = threadIdx.x;
    const int lane = t & 63;
    const int wid = t >> 6;
    const int wr = wid >> 1, wc = wid & 1;
    const int m0 = blockIdx.y * BM;
    const int n0 = blockIdx.x * BN;
    const int z = blockIdx.z;
    const int lr = lane & 15, lg = lane >> 4, lr8 = lr & 7;

    __shared__ __bf16 As[BM * BK];   // swizzled [row][64]
    __shared__ __bf16 Bs[BN * BK];   // swizzled [col][64]

    f32x4 acc[4][2];
#pragma unroll
    for (int i = 0; i < 4; i++)
#pragma unroll
        for (int j = 0; j < 2; j++) acc[i][j] = (f32x4){0.f, 0.f, 0.f, 0.f};

    // ---- staging roles ----
    const int s_row = t >> 1;
    const int s_g0 = (t & 1) * 4;          // A: groups g0..g0+3 (k = g*8..)
    const int s_col = t >> 2;
    const int s_bg0 = (t & 3) * 2;         // B: groups bg0..bg0+1
    const int r8 = s_row & 7, c8 = s_col & 7;
    // LDS write offsets (element units)
    const int aw0 = (s_row << 6) + (((s_g0 + 0) ^ r8) << 3);
    const int aw1 = (s_row << 6) + (((s_g0 + 1) ^ r8) << 3);
    const int aw2 = (s_row << 6) + (((s_g0 + 2) ^ r8) << 3);
    const int aw3 = (s_row << 6) + (((s_g0 + 3) ^ r8) << 3);
    const int bw0 = (s_col << 6) + (((s_bg0 + 0) ^ c8) << 3);
    const int bw1 = (s_col << 6) + (((s_bg0 + 1) ^ c8) << 3);
    // fragment read bases
    const int rA0 = (wr * 64 + 0 * 16 + lr) << 6;
    const int rA1 = (wr * 64 + 1 * 16 + lr) << 6;
    const int rA2 = (wr * 64 + 2 * 16 + lr) << 6;
    const int rA3 = (wr * 64 + 3 * 16 + lr) << 6;
    const int cB0 = (wc * 32 + 0 * 16 + lr) << 6;
    const int cB1 = (wc * 32 + 1 * 16 + lr) << 6;

    // ---- A source bases ----
    const __bf16* a_srcb = nullptr;
    const float* a_srcf = nullptr;
    const __bf16* e_src = nullptr;
    if (AMODE == 0)
        a_srcb = (const __bf16*)Aptr + z * strideA + (size_t)(m0 + s_row) * lda + s_g0 * 8;
    if (AMODE == 2) {
        int gr = m0 + s_row;
        int srow = order[gr >> 6] * 64 + (gr & 63);
        a_srcf = (const float*)Aptr + (size_t)srow * lda + s_g0 * 8;
    }
    if (AMODE == 1) e_src = embb + (size_t)widx_t[s_row] * NEM + s_g0 * 8;
    const __bf16* g_src = (AMODE == 1) ? gb + (size_t)s_row * NEM + s_g0 * 8 - NEM : nullptr;
    const __bf16* h_src = (AMODE == 1) ? hb + (size_t)s_row * NH + s_g0 * 8 - 2 * NEM : nullptr;

    const __bf16* b_src = Bt + z * strideB + (size_t)(n0 + s_col) * ldb + s_bg0 * 8;
    const bool b_ok = (n0 + s_col) < N;

    auto loadA = [&](int k0, bf16x8& a0, bf16x8& a1, bf16x8& a2, bf16x8& a3) {
        if (AMODE == 0) {
            const bf16x8* p = (const bf16x8*)(a_srcb + k0);
            a0 = p[0]; a1 = p[1]; a2 = p[2]; a3 = p[3];
        } else if (AMODE == 2) {
            const float4* p = (const float4*)(a_srcf + k0);
            float4 f0 = p[0], f1 = p[1], f2 = p[2], f3 = p[3];
            float4 f4 = p[4], f5 = p[5], f6 = p[6], f7 = p[7];
            a0 = (bf16x8){(__bf16)f0.x, (__bf16)f0.y, (__bf16)f0.z, (__bf16)f0.w,
                          (__bf16)f1.x, (__bf16)f1.y, (__bf16)f1.z, (__bf16)f1.w};
            a1 = (bf16x8){(__bf16)f2.x, (__bf16)f2.y, (__bf16)f2.z, (__bf16)f2.w,
                          (__bf16)f3.x, (__bf16)f3.y, (__bf16)f3.z, (__bf16)f3.w};
            a2 = (bf16x8){(__bf16)f4.x, (__bf16)f4.y, (__bf16)f4.z, (__bf16)f4.w,
                          (__bf16)f5.x, (__bf16)f5.y, (__bf16)f5.z, (__bf16)f5.w};
            a3 = (bf16x8){(__bf16)f6.x, (__bf16)f6.y, (__bf16)f6.z, (__bf16)f6.w,
                          (__bf16)f7.x, (__bf16)f7.y, (__bf16)f7.z, (__bf16)f7.w};
        } else {
            int kk = k0 + s_g0 * 8;
            const __bf16* p;
            if (kk < NEM) p = e_src + k0;
            else if (kk < 2 * NEM) p = g_src + k0;
            else p = h_src + k0;
            const bf16x8* pv = (const bf16x8*)p;
            a0 = pv[0]; a1 = pv[1]; a2 = pv[2]; a3 = pv[3];
        }
    };
    auto loadB = [&](int k0, bf16x8& b0, bf16x8& b1) {
        if (b_ok) {
            const bf16x8* p = (const bf16x8*)(b_src + k0);
            b0 = p[0]; b1 = p[1];
        } else {
            bf16x8 zv = {};
            b0 = zv; b1 = zv;
        }
    };
    auto writeS = [&](bf16x8 a0, bf16x8 a1, bf16x8 a2, bf16x8 a3, bf16x8 b0, bf16x8 b1) {
        *(bf16x8*)&As[aw0] = a0; *(bf16x8*)&As[aw1] = a1;
        *(bf16x8*)&As[aw2] = a2; *(bf16x8*)&As[aw3] = a3;
        *(bf16x8*)&Bs[bw0] = b0; *(bf16x8*)&Bs[bw1] = b1;
    };
    auto compute = [&]() {
#pragma unroll
        for (int ks = 0; ks < 2; ks++) {
            const int gsw = ((ks * 4 + lg) ^ lr8) << 3;
            bf16x8 af0 = *(const bf16x8*)&As[rA0 + gsw];
            bf16x8 af1 = *(const bf16x8*)&As[rA1 + gsw];
            bf16x8 af2 = *(const bf16x8*)&As[rA2 + gsw];
            bf16x8 af3 = *(const bf16x8*)&As[rA3 + gsw];
            bf16x8 bv0 = *(const bf16x8*)&Bs[cB0 + gsw];
            bf16x8 bv1 = *(const bf16x8*)&Bs[cB1 + gsw];
            acc[0][0] = __builtin_amdgcn_mfma_f32_16x16x32_bf16(af0, bv0, acc[0][0], 0, 0, 0);
            acc[0][1] = __builtin_amdgcn_mfma_f32_16x16x32_bf16(af0, bv1, acc[0][1], 0, 0, 0);
            acc[1][0] = __builtin_amdgcn_mfma_f32_16x16x32_bf16(af1, bv0, acc[1][0], 0, 0, 0);
            acc[1][1] = __builtin_amdgcn_mfma_f32_16x16x32_bf16(af1, bv1, acc[1][1], 0, 0, 0);
            acc[2][0] = __builtin_amdgcn_mfma_f32_16x16x32_bf16(af2, bv0, acc[2][0], 0, 0, 0);
            acc[2][1] = __builtin_amdgcn_mfma_f32_16x16x32_bf16(af2, bv1, acc[2][1], 0, 0, 0);
            acc[3][0] = __builtin_amdgcn_mfma_f32_16x16x32_bf16(af3, bv0, acc[3][0], 0, 0, 0);
            acc[3][1] = __builtin_amdgcn_mfma_f32_16x16x32_bf16(af3, bv1, acc[3][1], 0, 0, 0);
        }
    };

    bf16x8 a0, a1, a2, a3, b0, b1;
    bf16x8 c0, c1, c2, c3, d0, d1;
    loadA(0, a0, a1, a2, a3);
    loadB(0, b0, b1);
    for (int k0 = 0; k0 < K; k0 += 2 * BK) {
        writeS(a0, a1, a2, a3, b0, b1);
        __syncthreads();
        loadA(k0 + BK, c0, c1, c2, c3);   // K % 128 == 0 -> always in range
        loadB(k0 + BK, d0, d1);
        compute();
        __syncthreads();
        writeS(c0, c1, c2, c3, d0, d1);
        __syncthreads();
        if (k0 + 2 * BK < K) {
            loadA(k0 + 2 * BK, a0, a1, a2, a3);
            loadB(k0 + 2 * BK, b0, b1);
        }
        compute();
        __syncthreads();
    }

    // ---- epilogue ----
    const float* bias_z = bias + z * strideBias;
    float* Cf = (float*)Cptr + z * strideC;
    __bf16* Cb = (__bf16*)Cptr + z * strideC;
#pragma unroll
    for (int mi = 0; mi < 4; mi++) {
#pragma unroll
        for (int ni = 0; ni < 2; ni++) {
            int col = n0 + wc * 32 + ni * 16 + lr;
            if (col < N) {
                float bb = bias_z[col];
#pragma unroll
                for (int rr = 0; rr < 4; rr++) {
                    int row = m0 + wr * 64 + mi * 16 + lg * 4 + rr;
                    float v = acc[mi][ni][rr] + bb;
                    if (RELU) v = fmaxf(v, 0.f);
                    if (OUTBF) Cb[(size_t)row * ldc + col] = (__bf16)v;
                    else Cf[(size_t)row * ldc + col] = v;
                }
            }
        }
    }
}

// ---------------- LSTM pointwise ----------------
__global__ void lstm_pointwise(const float* __restrict__ gates, float* __restrict__ c,
                               __bf16* __restrict__ h, __bf16* __restrict__ s) {
    int tid = blockIdx.x * 256 + threadIdx.x;   // b*NH + j
    int b = tid >> 10, j = tid & 1023;
    const float* gr = gates + (size_t)b * 5120;
    float ig = sigf(gr[j]);
    float fg = sigf(gr[1024 + j]);
    float gg = tanhf(gr[2048 + j]);
    float og = sigf(gr[3072 + j]);
    float sgg = sigf(gr[4096 + j]);
    float cn = fg * c[tid] + ig * gg;
    float tc = tanhf(cn);
    c[tid] = cn;
    h[tid] = (__bf16)(og * tc);
    s[tid] = (__bf16)(sgg * tc);
}

// ---------------- attention ----------------
__global__ __launch_bounds__(256) void attn_kernel(
    const __bf16* __restrict__ VA, const __bf16* __restrict__ V,
    const float* __restrict__ hp, const float* __restrict__ sws,
    const float* __restrict__ wa, const __bf16* __restrict__ s,
    const __bf16* __restrict__ h, __bf16* __restrict__ z) {
    __shared__ float zscore[NKK + 1];
    __shared__ float alpha_s[NKK + 1];
    int b = blockIdx.x;
    int wave = threadIdx.x >> 6, lane = threadIdx.x & 63;

    float hp_reg[16], wa_reg[16];
    {
        const float* hb2 = hp + (size_t)b * NH + lane * 16;
        const float* wb = wa + lane * 16;
#pragma unroll
        for (int q = 0; q < 4; q++) {
            float4 hv = *(const float4*)(hb2 + q * 4);
            float4 wv = *(const float4*)(wb + q * 4);
            hp_reg[q * 4 + 0] = hv.x; hp_reg[q * 4 + 1] = hv.y;
            hp_reg[q * 4 + 2] = hv.z; hp_reg[q * 4 + 3] = hv.w;
            wa_reg[q * 4 + 0] = wv.x; wa_reg[q * 4 + 1] = wv.y;
            wa_reg[q * 4 + 2] = wv.z; wa_reg[q * 4 + 3] = wv.w;
        }
    }
    for (int k = wave; k <= NKK; k += 4) {
        float p = 0.f;
        if (k < NKK) {
            const bf16x8* row = (const bf16x8*)(VA + ((size_t)(b * NKK + k)) * NH + lane * 16);
            bf16x8 v0 = row[0], v1 = row[1];
#pragma unroll
            for (int j = 0; j < 8; j++) {
                p += tanhf((float)v0[j] + hp_reg[j]) * wa_reg[j];
                p += tanhf((float)v1[j] + hp_reg[8 + j]) * wa_reg[8 + j];
            }
        } else {
            const float* sp = sws + (size_t)b * NH + lane * 16;
#pragma unroll
            for (int j = 0; j < 16; j++) p += tanhf(sp[j] + hp_reg[j]) * wa_reg[j];
        }
        for (int off = 32; off; off >>= 1) p += __shfl_down(p, off);
        if (lane == 0) zscore[k] = p;
    }
    __syncthreads();
    if (threadIdx.x == 0) {
        float mx = zscore[0];
        for (int i = 1; i <= NKK; i++) mx = fmaxf(mx, zscore[i]);
        float ssum = 0.f;
        for (int i = 0; i <= NKK; i++) { float e = expf(zscore[i] - mx); alpha_s[i] = e; ssum += e; }
        float inv = 1.f / ssum;
        for (int i = 0; i <= NKK; i++) alpha_s[i] *= inv;
    }
    __syncthreads();
    float beta = alpha_s[NKK];
    for (int jj = threadIdx.x; jj < NH; jj += 256) {
        float ctx = 0.f;
        const __bf16* vp = V + ((size_t)b * NKK) * NH + jj;
#pragma unroll 8
        for (int k = 0; k < NKK; k++) ctx += alpha_s[k] * (float)vp[(size_t)k * NH];
        float zv = beta * (float)s[b * NH + jj] + (1.f - beta) * ctx + (float)h[b * NH + jj];
        z[b * NH + jj] = (__bf16)zv;
    }
}

// ---------------- vocab softmax + mask ----------------
__global__ __launch_bounds__(256) void vocab_softmax(const float* __restrict__ logits,
                                                     const int* __restrict__ lens_s, int t,
                                                     float* __restrict__ pred) {
    int b = blockIdx.x;
    float* out = pred + (size_t)b * NT * NVOC + (size_t)t * NVOC;
    if (t >= lens_s[b]) {
        for (int v = threadIdx.x; v < NVOC; v += 256) out[v] = 0.f;
        return;
    }
    const float* lg = logits + (size_t)b * NVOC;
    float mx = -1e30f;
    for (int v = threadIdx.x; v < NVOC; v += 256) mx = fmaxf(mx, lg[v]);
    __shared__ float sred[4];
    for (int off = 32; off; off >>= 1) mx = fmaxf(mx, __shfl_down(mx, off));
    if ((threadIdx.x & 63) == 0) sred[threadIdx.x >> 6] = mx;
    __syncthreads();
    mx = fmaxf(fmaxf(sred[0], sred[1]), fmaxf(sred[2], sred[3]));
    float ssum = 0.f;
    for (int v = threadIdx.x; v < NVOC; v += 256) ssum += expf(lg[v] - mx);
    for (int off = 32; off; off >>= 1) ssum += __shfl_down(ssum, off);
    __shared__ float sred2[4];
    if ((threadIdx.x & 63) == 0) sred2[threadIdx.x >> 6] = ssum;
    __syncthreads();
    ssum = sred2[0] + sred2[1] + sred2[2] + sred2[3];
    float inv = 1.f / ssum;
    for (int v = threadIdx.x; v < NVOC; v += 256) out[v] = expf(lg[v] - mx) * inv;
}

extern "C" void kernel_launch(void* const* d_in, const int* in_sizes, int n_in,
                              void* d_out, int out_size, void* d_ws, size_t ws_size,
                              hipStream_t stream) {
    const float* im = (const float*)d_in[0];
    const int* w_in = (const int*)d_in[1];
    const int* cap = (const int*)d_in[2];
    const float* emb = (const float*)d_in[3];
    const float* W_enc = (const float*)d_in[4];
    const float* b_enc = (const float*)d_in[5];
    const float* W_glob = (const float*)d_in[6];
    const float* b_glob = (const float*)d_in[7];
    const float* W_ih = (const float*)d_in[8];
    const float* b_ih = (const float*)d_in[9];
    const float* W_hh = (const float*)d_in[10];
    const float* b_hh = (const float*)d_in[11];
    const float* W_xg = (const float*)d_in[12];
    const float* b_xg = (const float*)d_in[13];
    const float* W_hg = (const float*)d_in[14];
    const float* b_hg = (const float*)d_in[15];
    const float* Wv = (const float*)d_in[16];
    const float* bv = (const float*)d_in[17];
    const float* Ws = (const float*)d_in[18];
    const float* bs = (const float*)d_in[19];
    const float* Wh = (const float*)d_in[20];
    const float* bh = (const float*)d_in[21];
    const float* wa = (const float*)d_in[22];
    // ba cancels in softmax(65)
    const float* W_out = (const float*)d_in[24];
    const float* b_out = (const float*)d_in[25];

    float* out = (float*)d_out;
    float* pred = out;
    float* out_target = out + (size_t)NB * NT * NVOC;
    float* out_lens = out_target + NB * NT;

    char* p = (char*)d_ws;
    size_t off = 0;
    auto carve = [&](size_t bytes) {
        void* r = p + off;
        off += (bytes + 255) & ~(size_t)255;
        return r;
    };
    int* order = (int*)carve(NB * 4);
    int* lens_s = (int*)carve(NB * 4);
    int* widx = (int*)carve(NT * NB * 4);
    __bf16* embb = (__bf16*)carve((size_t)NVOC * NEM * 2);
    __bf16* Wstep_t = (__bf16*)carve((size_t)5120 * 2048 * 2);
    __bf16* W2t = (__bf16*)carve((size_t)2 * 1024 * 1024 * 2);
    __bf16* Wout_t = (__bf16*)carve((size_t)NVOC * 1024 * 2);
    __bf16* Wglob_t = (__bf16*)carve((size_t)512 * 1536 * 2);
    __bf16* Wenc_t = (__bf16*)carve((size_t)1024 * 1536 * 2);
    __bf16* Wv_t = (__bf16*)carve((size_t)1024 * 1024 * 2);
    float* bstep = (float*)carve(5120 * 4);
    float* b2 = (float*)carve(2048 * 4);
    __bf16* meanb = (__bf16*)carve((size_t)NB * ND * 2);
    __bf16* g_bf = (__bf16*)carve((size_t)NB * NEM * 2);
    __bf16* V_bf = (__bf16*)carve((size_t)NB * NKK * NH * 2);
    __bf16* VA_bf = (__bf16*)carve((size_t)NB * NKK * NH * 2);
    float* gates = (float*)carve((size_t)NB * 5120 * 4);
    __bf16* hs_bf = (__bf16*)carve((size_t)2 * NB * NH * 2);   // [h ; s]
    float* c = (float*)carve((size_t)NB * NH * 4);
    float* hpsws = (float*)carve((size_t)2 * NB * NH * 4);     // [hp ; sws]
    __bf16* z_bf = (__bf16*)carve((size_t)NB * NH * 2);
    float* logits = (float*)carve((size_t)NB * NVOC * 4);
    if (off > ws_size) return;  // fail loudly via absmax if ws too small

    __bf16* h_bf = hs_bf;
    __bf16* s_bf = hs_bf + (size_t)NB * NH;
    float* hp = hpsws;
    float* sws = hpsws + (size_t)NB * NH;

    // ---- one-time setup ----
    sort_kernel<<<1, NB, 0, stream>>>(cap, w_in, out_target, out_lens, order, lens_s, widx);
    init_kernel<<<(NB * NH) / 256, 256, 0, stream>>>(h_bf, c);
    pack_biases<<<20, 256, 0, stream>>>(b_ih, b_hh, b_xg, b_hg, bh, bs, bstep, b2);
    conv_bf16_vec<<<(NVOC * NEM / 4 + 255) / 256, 256, 0, stream>>>(emb, embb, NVOC * NEM / 4);
    // weight transposes: dst[n][k] = src[k][n], f32 -> bf16
    transpose_pack<<<dim3(8, 24), 256, 0, stream>>>(W_glob, 512, 1536, 512, Wglob_t, 1536);
    transpose_pack<<<dim3(16, 24), 256, 0, stream>>>(W_enc, 1024, 1536, 1024, Wenc_t, 1536);
    transpose_pack<<<dim3(16, 16), 256, 0, stream>>>(Wv, 1024, 1024, 1024, Wv_t, 1024);
    transpose_pack<<<dim3(64, 16), 256, 0, stream>>>(W_ih, 4096, 1024, 4096, Wstep_t, 2048);
    transpose_pack<<<dim3(64, 16), 256, 0, stream>>>(W_hh, 4096, 1024, 4096, Wstep_t + 1024, 2048);
    transpose_pack<<<dim3(16, 16), 256, 0, stream>>>(W_xg, 1024, 1024, 1024,
                                                     Wstep_t + (size_t)4096 * 2048, 2048);
    transpose_pack<<<dim3(16, 16), 256, 0, stream>>>(W_hg, 1024, 1024, 1024,
                                                     Wstep_t + (size_t)4096 * 2048 + 1024, 2048);
    transpose_pack<<<dim3(16, 16), 256, 0, stream>>>(Wh, 1024, 1024, 1024, W2t, 1024);
    transpose_pack<<<dim3(16, 16), 256, 0, stream>>>(Ws, 1024, 1024, 1024, W2t + (size_t)1024 * 1024, 1024);
    transpose_pack<<<dim3(157, 16), 256, 0, stream>>>(W_out, NVOC, 1024, NVOC, Wout_t, 1024);
    meanim_kernel<<<NB, 256, 0, stream>>>(im, order, meanb);

    // g = relu(meanim @ W_glob + b_glob)   (128 x 512, K=1536), bf16 out
    gemm_bt<0, true, true><<<dim3(NEM / BN, 1), 256, 0, stream>>>(
        meanb, ND, Wglob_t, ND, b_glob, g_bf, NEM, NB, NEM, ND, 0, 0, 0, 0,
        nullptr, nullptr, nullptr, nullptr, nullptr);
    // V = relu(im[order] @ W_enc + b_enc)  (8192 x 1024, K=1536), bf16 out
    gemm_bt<2, true, true><<<dim3(NH / BN, (NB * NKK) / BM), 256, 0, stream>>>(
        im, ND, Wenc_t, ND, b_enc, V_bf, NH, NB * NKK, NH, ND, 0, 0, 0, 0,
        nullptr, nullptr, nullptr, nullptr, order);
    // VA = V @ Wv + bv                     (8192 x 1024, K=1024), bf16 out
    gemm_bt<0, false, true><<<dim3(NH / BN, (NB * NKK) / BM), 256, 0, stream>>>(
        V_bf, NH, Wv_t, NH, bv, VA_bf, NH, NB * NKK, NH, NH, 0, 0, 0, 0,
        nullptr, nullptr, nullptr, nullptr, nullptr);

    // ---- 30 timesteps ----
    for (int t = 0; t < NT; t++) {
        // gates|sg = [emb|g|h] @ Wstep + bstep   (128 x 5120, K=2048), f32 out
        gemm_bt<1, false, false><<<dim3(5120 / BN, 1), 256, 0, stream>>>(
            nullptr, 0, Wstep_t, 2048, bstep, gates, 5120, NB, 5120, 2048, 0, 0, 0, 0,
            embb, g_bf, h_bf, widx + t * NB, nullptr);
        lstm_pointwise<<<(NB * NH) / 256, 256, 0, stream>>>(gates, c, h_bf, s_bf);
        // [hp ; sws] = [h ; s] @ [Wh ; Ws] + [bh ; bs]   (z-batched, f32 out)
        gemm_bt<0, false, false><<<dim3(NH / BN, 1, 2), 256, 0, stream>>>(
            hs_bf, NH, W2t, NH, b2, hpsws, NH, NB, NH, NH,
            (size_t)NB * NH, (size_t)NH * NH, (size_t)NH, (size_t)NB * NH,
            nullptr, nullptr, nullptr, nullptr, nullptr);
        attn_kernel<<<NB, 256, 0, stream>>>(VA_bf, V_bf, hp, sws, wa, s_bf, h_bf, z_bf);
        // logits = z @ W_out + b_out        (128 x 10000, K=1024), f32 out
        gemm_bt<0, false, false><<<dim3((NVOC + BN - 1) / BN, 1), 256, 0, stream>>>(
            z_bf, NH, Wout_t, NH, b_out, logits, NVOC, NB, NVOC, NH, 0, 0, 0, 0,
            nullptr, nullptr, nullptr, nullptr, nullptr);
        vocab_softmax<<<NB, 256, 0, stream>>>(logits, lens_s, t, pred);
    }
}